// Round 9
// baseline (520.863 us; speedup 1.0000x reference)
//
#include <hip/hip_runtime.h>
#include <hip/hip_bf16.h>

typedef short bf16x8 __attribute__((ext_vector_type(8)));
typedef float f32x4 __attribute__((ext_vector_type(4)));

#define HID 128
#define NRAD 6
#define TILE 64

static __device__ __forceinline__ unsigned short f2bf(float f) {
    union { float f; unsigned u; } v; v.f = f;
    unsigned r = v.u + 0x7FFFu + ((v.u >> 16) & 1u);
    return (unsigned short)(r >> 16);
}

static __device__ __forceinline__ float swishf(float z) {
    return z * __builtin_amdgcn_rcpf(1.0f + __expf(-z));
}

// ---------------------------------------------------------------------------
// Precompute: P1[v] = emb[v]@W1 + b_lin, P2[v] = emb[v]@W2, Wt = (W3^T) bf16
// ---------------------------------------------------------------------------
__global__ void precompute_kernel(const float* __restrict__ emb,
                                  const float* __restrict__ w_lin,
                                  const float* __restrict__ b_lin,
                                  float* __restrict__ P1,
                                  float* __restrict__ P2,
                                  unsigned short* __restrict__ Wt) {
    const int b = blockIdx.x;
    const int t = threadIdx.x; // 0..127 = output column n
    if (b < 190) {
        const int v = (b < 95) ? b : b - 95;
        const float* W = w_lin + (b < 95 ? 0 : HID * HID);
        float acc = (b < 95) ? b_lin[t] : 0.0f;
        #pragma unroll 4
        for (int k = 0; k < HID; ++k)
            acc = fmaf(emb[v * HID + k], W[k * HID + t], acc);
        (b < 95 ? P1 : P2)[v * HID + t] = acc;
    } else {
        const int kr = b - 190; // 0..127
        Wt[t * HID + kr] = f2bf(w_lin[(2 * HID + kr) * HID + t]);
    }
}

// ---------------------------------------------------------------------------
// Persistent edge kernel — LDS READ-ONLY after one staging barrier.
// Software-pipelined rbf/ei/ej one tile ahead; x[] gather resolved at loop
// top. Epilogue in 2 batches of 4 fragments with prefetched P1/P2 operands
// (bounds live registers so 3 waves/SIMD fit). Non-temporal stores (proven
// faster than L2 write path despite partial-granule inflation).
// ---------------------------------------------------------------------------
__global__ __launch_bounds__(256)
__attribute__((amdgpu_waves_per_eu(3))) void edge_kernel(
    const float* __restrict__ rbf, const int* __restrict__ ei,
    const int* __restrict__ ej, const int* __restrict__ x,
    const float* __restrict__ w_rbf, const float* __restrict__ b_rbf,
    const float* __restrict__ P1, const float* __restrict__ P2,
    const unsigned short* __restrict__ Wt,
    float* __restrict__ out, int E, int ntiles)
{
    __shared__ __align__(16) float s_w[7 * HID];             // rows 0..5: w_rbf, row 6: b_rbf
    __shared__ __align__(16) unsigned short sB[HID * HID];   // W3^T bf16, XOR-swizzled

    const int t = threadIdx.x;
    const int w = t >> 6, l = t & 63, lr = l & 15, lg = l >> 4;

    // ---- one-time read-only staging ----
    for (int idx = t; idx < NRAD * HID; idx += 256) s_w[idx] = w_rbf[idx];
    if (t < HID) s_w[6 * HID + t] = b_rbf[t];
    {
        const uint4* g = (const uint4*)Wt;
        #pragma unroll
        for (int q = 0; q < 8; ++q) {
            int gi = q * 256 + t;                 // coalesced
            int n = gi >> 4, cc = gi & 15;
            uint4 v = g[gi];
            *(uint4*)((char*)sB + n * 256 + ((cc * 16) ^ ((n & 7) << 4))) = v;
        }
    }
    __syncthreads();   // the ONLY barrier; LDS never written again

    const int n0base = lg * 8;
    const int elane = w * 16 + lr;               // lane's edge offset within tile

    int tile = blockIdx.x;

    // ---- pipeline preload: tile 0 inputs ----
    float2 r01, r23, r45;
    int ii, jj;
    {
        const int e0 = min(tile * TILE + elane, E - 1);
        const float* rp = rbf + (size_t)e0 * NRAD;
        r01 = *(const float2*)(rp);
        r23 = *(const float2*)(rp + 2);
        r45 = *(const float2*)(rp + 4);
        ii = ei[e0];
        jj = ej[e0];
    }

    for (; tile < ntiles; tile += gridDim.x) {
        const int e = tile * TILE + elane;

        // resolve current tile's x-gathers now (consumed in epilogue ~1000cy later)
        const int xi = x[ii];
        const int xj = x[jj];
        const float r0 = r01.x, r1 = r01.y, r2 = r23.x,
                    r3 = r23.y, r4 = r45.x, r5 = r45.y;

        // issue NEXT tile's streaming loads (hidden under this tile's compute)
        float2 n01, n23, n45;
        int ni, nj;
        {
            const int tn = tile + gridDim.x;
            const int en = min((tn < ntiles ? tn : tile) * TILE + elane, E - 1);
            const float* rp = rbf + (size_t)en * NRAD;
            n01 = *(const float2*)(rp);
            n23 = *(const float2*)(rp + 2);
            n45 = *(const float2*)(rp + 4);
            ni = ei[en];
            nj = ej[en];
        }

        // ---- build the 4 B-fragments (r slice) in registers ----
        bf16x8 af[4];
        #pragma unroll
        for (int kk = 0; kk < 4; ++kk) {
            const int n0 = kk * 32 + n0base;
            f32x4 z0 = *(const f32x4*)(s_w + 6 * HID + n0);
            f32x4 z1 = *(const f32x4*)(s_w + 6 * HID + n0 + 4);
            #define RSTEP(q, rq)                                           \
            {                                                              \
                const f32x4 w0 = *(const f32x4*)(s_w + (q) * HID + n0);    \
                const f32x4 w1 = *(const f32x4*)(s_w + (q) * HID + n0 + 4);\
                _Pragma("unroll")                                          \
                for (int u = 0; u < 4; ++u) {                              \
                    z0[u] = fmaf(rq, w0[u], z0[u]);                        \
                    z1[u] = fmaf(rq, w1[u], z1[u]);                        \
                }                                                          \
            }
            RSTEP(0, r0) RSTEP(1, r1) RSTEP(2, r2)
            RSTEP(3, r3) RSTEP(4, r4) RSTEP(5, r5)
            #undef RSTEP
            union { unsigned short s[8]; bf16x8 v; } pk;
            #pragma unroll
            for (int u = 0; u < 4; ++u) {
                pk.s[u]     = f2bf(swishf(z0[u]));
                pk.s[4 + u] = f2bf(swishf(z1[u]));
            }
            af[kk] = pk.v;
        }

        // ---- per-fragment MFMA + epilogue, 2 batches of 4 fragments ----
        const bool valid = (e < E);
        const float* p1 = P1 + xi * HID;     // always-valid table rows
        const float* p2 = P2 + xj * HID;
        float* op = out + (size_t)e * HID;

        #pragma unroll
        for (int h = 0; h < 2; ++h) {
            // prefetch this batch's P1/P2 operands (unconditional: tables)
            f32x4 a1[4], a2[4];
            #pragma unroll
            for (int fi = 0; fi < 4; ++fi) {
                const int n0 = (h * 4 + fi) * 16 + lg * 4;
                a1[fi] = *(const f32x4*)(p1 + n0);
                a2[fi] = *(const f32x4*)(p2 + n0);
            }
            #pragma unroll
            for (int fi = 0; fi < 4; ++fi) {
                const int f = h * 4 + fi;
                f32x4 acc = (f32x4){0.f, 0.f, 0.f, 0.f};
                const int rowB = f * 16 + lr;
                const int rB = rowB * 256, sw = (rowB & 7) << 4;
                #pragma unroll
                for (int kk = 0; kk < 4; ++kk) {
                    const int colb = kk * 64 + lg * 16;
                    bf16x8 bb = *(const bf16x8*)((const char*)sB + rB + (colb ^ sw));
                    acc = __builtin_amdgcn_mfma_f32_16x16x32_bf16(bb, af[kk], acc, 0, 0, 0);
                }
                if (valid) {
                    const int n0 = f * 16 + lg * 4;
                    f32x4 v;
                    #pragma unroll
                    for (int u = 0; u < 4; ++u)
                        v[u] = swishf(acc[u] + a1[fi][u] + a2[fi][u]);
                    __builtin_nontemporal_store(v, (f32x4*)(op + n0));
                }
            }
        }

        // rotate pipeline registers
        r01 = n01; r23 = n23; r45 = n45; ii = ni; jj = nj;
    }
}

extern "C" void kernel_launch(void* const* d_in, const int* in_sizes, int n_in,
                              void* d_out, int out_size, void* d_ws, size_t ws_size,
                              hipStream_t stream) {
    const int*   x     = (const int*)  d_in[0];
    const float* rbf   = (const float*)d_in[1];
    const int*   ei    = (const int*)  d_in[2];
    const int*   ej    = (const int*)  d_in[3];
    const float* emb   = (const float*)d_in[4];
    const float* w_rbf = (const float*)d_in[5];
    const float* b_rbf = (const float*)d_in[6];
    const float* w_lin = (const float*)d_in[7];
    const float* b_lin = (const float*)d_in[8];
    float* out = (float*)d_out;
    const int E = in_sizes[2];

    // workspace: P1 (95*128 f32), P2, Wt (128x128 bf16)
    float* P1 = (float*)d_ws;
    float* P2 = (float*)((char*)d_ws + 49152);
    unsigned short* Wt = (unsigned short*)((char*)d_ws + 98304);

    hipLaunchKernelGGL(precompute_kernel, dim3(318), dim3(128), 0, stream,
                       emb, w_lin, b_lin, P1, P2, Wt);

    const int ntiles = (E + TILE - 1) / TILE;
    const int nblk = ntiles < 1024 ? ntiles : 1024;
    hipLaunchKernelGGL(edge_kernel, dim3(nblk), dim3(256), 0, stream,
                       rbf, ei, ej, x, w_rbf, b_rbf, P1, P2, Wt, out, E, ntiles);
}

// Round 10
// 129.759 us; speedup vs baseline: 4.0141x; 4.0141x over previous
//
#include <hip/hip_runtime.h>
#include <hip/hip_bf16.h>

typedef short bf16x8 __attribute__((ext_vector_type(8)));
typedef float f32x4 __attribute__((ext_vector_type(4)));

#define HID 128
#define NRAD 6
#define TILE 64

static __device__ __forceinline__ unsigned short f2bf(float f) {
    union { float f; unsigned u; } v; v.f = f;
    unsigned r = v.u + 0x7FFFu + ((v.u >> 16) & 1u);
    return (unsigned short)(r >> 16);
}

static __device__ __forceinline__ float swishf(float z) {
    return z * __builtin_amdgcn_rcpf(1.0f + __expf(-z));
}

// ---------------------------------------------------------------------------
// Precompute: P1[v] = emb[v]@W1 + b_lin, P2[v] = emb[v]@W2, Wt = (W3^T) bf16
// ---------------------------------------------------------------------------
__global__ void precompute_kernel(const float* __restrict__ emb,
                                  const float* __restrict__ w_lin,
                                  const float* __restrict__ b_lin,
                                  float* __restrict__ P1,
                                  float* __restrict__ P2,
                                  unsigned short* __restrict__ Wt) {
    const int b = blockIdx.x;
    const int t = threadIdx.x; // 0..127 = output column n
    if (b < 190) {
        const int v = (b < 95) ? b : b - 95;
        const float* W = w_lin + (b < 95 ? 0 : HID * HID);
        float acc = (b < 95) ? b_lin[t] : 0.0f;
        #pragma unroll 4
        for (int k = 0; k < HID; ++k)
            acc = fmaf(emb[v * HID + k], W[k * HID + t], acc);
        (b < 95 ? P1 : P2)[v * HID + t] = acc;
    } else {
        const int kr = b - 190; // 0..127
        Wt[t * HID + kr] = f2bf(w_lin[(2 * HID + kr) * HID + t]);
    }
}

// ---------------------------------------------------------------------------
// Persistent edge kernel — shared LDS (s_w, sB) READ-ONLY after one barrier.
// Round-6 pipeline (rbf/ei/ej one tile ahead, x[] gather at loop top) +
// NEW: per-wave LDS output staging. Each wave writes its 16x512B output
// tile to a PRIVATE LDS buffer (wave-synchronous, no barrier), then stores
// with 64 lanes covering 1KB contiguous per instruction -> non-temporal
// stores hit full 64B granules (fixes the 43% write inflation) while still
// bypassing the L2 write path (which round 8 showed costs more).
// ---------------------------------------------------------------------------
__global__ __launch_bounds__(256, 1) void edge_kernel(
    const float* __restrict__ rbf, const int* __restrict__ ei,
    const int* __restrict__ ej, const int* __restrict__ x,
    const float* __restrict__ w_rbf, const float* __restrict__ b_rbf,
    const float* __restrict__ P1, const float* __restrict__ P2,
    const unsigned short* __restrict__ Wt,
    float* __restrict__ out, int E, int ntiles)
{
    __shared__ __align__(16) float s_w[7 * HID];             // w_rbf rows 0..5, b_rbf row 6
    __shared__ __align__(16) unsigned short sB[HID * HID];   // W3^T bf16, XOR-swizzled
    __shared__ __align__(16) float sOut[4 * 16 * HID];       // 32 KB: per-wave 16x512B staging

    const int t = threadIdx.x;
    const int w = t >> 6, l = t & 63, lr = l & 15, lg = l >> 4;

    // ---- one-time read-only staging ----
    for (int idx = t; idx < NRAD * HID; idx += 256) s_w[idx] = w_rbf[idx];
    if (t < HID) s_w[6 * HID + t] = b_rbf[t];
    {
        const uint4* g = (const uint4*)Wt;
        #pragma unroll
        for (int q = 0; q < 8; ++q) {
            int gi = q * 256 + t;                 // coalesced
            int n = gi >> 4, cc = gi & 15;
            uint4 v = g[gi];
            *(uint4*)((char*)sB + n * 256 + ((cc * 16) ^ ((n & 7) << 4))) = v;
        }
    }
    __syncthreads();   // the ONLY barrier; s_w/sB never written again

    const int n0base = lg * 8;
    const int elane = w * 16 + lr;               // lane's edge offset within tile
    char* const myOut = (char*)(sOut + w * 16 * HID);   // this wave's private staging

    int tile = blockIdx.x;

    // ---- pipeline preload: tile 0 inputs ----
    float2 r01, r23, r45;
    int ii, jj;
    {
        const int e0 = min(tile * TILE + elane, E - 1);
        const float* rp = rbf + (size_t)e0 * NRAD;
        r01 = *(const float2*)(rp);
        r23 = *(const float2*)(rp + 2);
        r45 = *(const float2*)(rp + 4);
        ii = ei[e0];
        jj = ej[e0];
    }

    for (; tile < ntiles; tile += gridDim.x) {
        const int e = tile * TILE + elane;

        // resolve current tile's x-gathers now (consumed ~1000cy later)
        const int xi = x[ii];
        const int xj = x[jj];
        const float r0 = r01.x, r1 = r01.y, r2 = r23.x,
                    r3 = r23.y, r4 = r45.x, r5 = r45.y;

        // issue NEXT tile's streaming loads (hidden under this tile's compute)
        float2 n01, n23, n45;
        int ni, nj;
        {
            const int tn = tile + gridDim.x;
            const int en = min((tn < ntiles ? tn : tile) * TILE + elane, E - 1);
            const float* rp = rbf + (size_t)en * NRAD;
            n01 = *(const float2*)(rp);
            n23 = *(const float2*)(rp + 2);
            n45 = *(const float2*)(rp + 4);
            ni = ei[en];
            nj = ej[en];
        }

        // ---- build the 4 B-fragments (r slice) in registers ----
        bf16x8 af[4];
        #pragma unroll
        for (int kk = 0; kk < 4; ++kk) {
            const int n0 = kk * 32 + n0base;
            f32x4 z0 = *(const f32x4*)(s_w + 6 * HID + n0);
            f32x4 z1 = *(const f32x4*)(s_w + 6 * HID + n0 + 4);
            #define RSTEP(q, rq)                                           \
            {                                                              \
                const f32x4 w0 = *(const f32x4*)(s_w + (q) * HID + n0);    \
                const f32x4 w1 = *(const f32x4*)(s_w + (q) * HID + n0 + 4);\
                _Pragma("unroll")                                          \
                for (int u = 0; u < 4; ++u) {                              \
                    z0[u] = fmaf(rq, w0[u], z0[u]);                        \
                    z1[u] = fmaf(rq, w1[u], z1[u]);                        \
                }                                                          \
            }
            RSTEP(0, r0) RSTEP(1, r1) RSTEP(2, r2)
            RSTEP(3, r3) RSTEP(4, r4) RSTEP(5, r5)
            #undef RSTEP
            union { unsigned short s[8]; bf16x8 v; } pk;
            #pragma unroll
            for (int u = 0; u < 4; ++u) {
                pk.s[u]     = f2bf(swishf(z0[u]));
                pk.s[4 + u] = f2bf(swishf(z1[u]));
            }
            af[kk] = pk.v;
        }

        // ---- per-fragment MFMA + epilogue math -> LDS staging (swizzled) ----
        const float* p1 = P1 + xi * HID;
        const float* p2 = P2 + xj * HID;

        #pragma unroll
        for (int f = 0; f < 8; ++f) {
            f32x4 acc = (f32x4){0.f, 0.f, 0.f, 0.f};
            const int rowB = f * 16 + lr;
            const int rB = rowB * 256, sw = (rowB & 7) << 4;
            #pragma unroll
            for (int kk = 0; kk < 4; ++kk) {
                const int colb = kk * 64 + lg * 16;
                bf16x8 bb = *(const bf16x8*)((const char*)sB + rB + (colb ^ sw));
                acc = __builtin_amdgcn_mfma_f32_16x16x32_bf16(bb, af[kk], acc, 0, 0, 0);
            }
            const int n0 = f * 16 + lg * 4;
            const f32x4 a1 = *(const f32x4*)(p1 + n0);
            const f32x4 a2 = *(const f32x4*)(p2 + n0);
            f32x4 v;
            #pragma unroll
            for (int u = 0; u < 4; ++u)
                v[u] = swishf(acc[u] + a1[u] + a2[u]);
            // stage: row lr (this wave's edge), byte col n0*4; swizzle on row
            *(f32x4*)(myOut + lr * 512 + ((n0 * 4) ^ ((lr & 7) << 4))) = v;
        }

        // ---- coalesced non-temporal stores: 64 lanes = 1KB contiguous ----
        // (wave-synchronous: compiler inserts lgkmcnt wait on the ds deps)
        const int wbase = tile * TILE + w * 16;   // wave's first edge
        #pragma unroll
        for (int it = 0; it < 8; ++it) {
            const int idx = it * 64 + l;          // chunk index in 16x32 grid
            const int row = idx >> 5, col = idx & 31;
            const f32x4 v = *(const f32x4*)(myOut + row * 512 +
                              ((col * 16) ^ ((row & 7) << 4)));
            if (wbase + row < E)
                __builtin_nontemporal_store(v,
                    (f32x4*)(out + (size_t)(wbase + row) * HID + col * 4));
        }

        // rotate pipeline registers
        r01 = n01; r23 = n23; r45 = n45; ii = ni; jj = nj;
    }
}

extern "C" void kernel_launch(void* const* d_in, const int* in_sizes, int n_in,
                              void* d_out, int out_size, void* d_ws, size_t ws_size,
                              hipStream_t stream) {
    const int*   x     = (const int*)  d_in[0];
    const float* rbf   = (const float*)d_in[1];
    const int*   ei    = (const int*)  d_in[2];
    const int*   ej    = (const int*)  d_in[3];
    const float* emb   = (const float*)d_in[4];
    const float* w_rbf = (const float*)d_in[5];
    const float* b_rbf = (const float*)d_in[6];
    const float* w_lin = (const float*)d_in[7];
    const float* b_lin = (const float*)d_in[8];
    float* out = (float*)d_out;
    const int E = in_sizes[2];

    // workspace: P1 (95*128 f32), P2, Wt (128x128 bf16)
    float* P1 = (float*)d_ws;
    float* P2 = (float*)((char*)d_ws + 49152);
    unsigned short* Wt = (unsigned short*)((char*)d_ws + 98304);

    hipLaunchKernelGGL(precompute_kernel, dim3(318), dim3(128), 0, stream,
                       emb, w_lin, b_lin, P1, P2, Wt);

    const int ntiles = (E + TILE - 1) / TILE;
    const int nblk = ntiles < 1024 ? ntiles : 1024;
    hipLaunchKernelGGL(edge_kernel, dim3(nblk), dim3(256), 0, stream,
                       rbf, ei, ej, x, w_rbf, b_rbf, P1, P2, Wt, out, E, ntiles);
}